// Round 10
// baseline (291.281 us; speedup 1.0000x reference)
//
#include <hip/hip_runtime.h>

// ---------------------------------------------------------------------------
// RelativeStructureAttention (Music-Transformer style) on MI355X / gfx950.
//   b=2, n=1024, dim=1024, HEADS=16, d_h=64. Inputs fp32 (+int32 idx), out fp32.
// Pipeline (round 10 = r9 + barrier-free attn + BN=64 gemm tiles):
//   0) prep        fused cast / pack_idx / build_tpad
//   1) gemm<2,64>  x@Wqkv^T -> QKVh (bf16, head-major), grid 768 (3/CU)
//   2) transpose_v V (b,h,n,64) -> Vt (b,h,64,n)   [r8-verified]
//   3) qe_gemm     QE[(bh,i),s] = Qrow . Tpad[s]  (fp16, stride 160)
//   4) attn        flash attention, NO barriers in jt loop: K frags from
//                  global (coalesced 2KB/wave), V^T frags from Vt global,
//                  per-wave C2 scratch, read-only qeh. One barrier total.
//   5) gemm<1,64>  O@Wo^T -> d_out (fp32), grid 256 (1/CU, was 0.5)
// ---------------------------------------------------------------------------

using bf16x8 = __attribute__((ext_vector_type(8))) short;
using f32x4  = __attribute__((ext_vector_type(4))) float;

__device__ __forceinline__ float bf2f(unsigned short u) {
  unsigned x = ((unsigned)u) << 16;
  float f;
  __builtin_memcpy(&f, &x, 4);
  return f;
}
__device__ __forceinline__ unsigned short f2bf(float f) {
  unsigned x;
  __builtin_memcpy(&x, &f, 4);
  unsigned r = (x + 0x7FFFu + ((x >> 16) & 1u)) >> 16;  // round-nearest-even
  return (unsigned short)r;
}

union B8 { bf16x8 v; unsigned short u[8]; };

// ---------------------------------------------------------------------------
// prep: blocks 0..1023 cast six fp32 tensors -> bf16; 1024..2047 pack idx;
//       block 2048 builds the padded 160x64 structure table (pre-scaled 1/8).
// ---------------------------------------------------------------------------
__global__ __launch_bounds__(256) void prep(
    const float* __restrict__ x,  const float* __restrict__ Wq,
    const float* __restrict__ Wk, const float* __restrict__ Wv,
    const float* __restrict__ Wo, const float* __restrict__ Er,
    const int* __restrict__ rb, const int* __restrict__ rp,
    const int* __restrict__ ro, const int* __restrict__ rs,
    const float* __restrict__ Tb, const float* __restrict__ Tp,
    const float* __restrict__ To, const float* __restrict__ Ts,
    unsigned short* __restrict__ x_bf, unsigned short* __restrict__ Wqkv,
    unsigned short* __restrict__ Wo_bf, unsigned short* __restrict__ Er_bf,
    unsigned* __restrict__ Pidx, unsigned short* __restrict__ Tpad)
{
  const int bid = blockIdx.x;
  const int tid = threadIdx.x;
  if (bid < 1024) {
    const int total = 1589248;  // 6,356,992 floats / 4
    for (int i = bid * 256 + tid; i < total; i += 1024 * 256) {
      const float4* s4;
      ushort4* d4;
      if (i < 524288)       { s4 = (const float4*)x  + i;           d4 = (ushort4*)x_bf  + i; }
      else if (i < 786432)  { s4 = (const float4*)Wq + (i-524288);  d4 = (ushort4*)Wqkv  + (i-524288); }
      else if (i < 1048576) { s4 = (const float4*)Wk + (i-786432);  d4 = (ushort4*)Wqkv  + (i-786432) + 262144; }
      else if (i < 1310720) { s4 = (const float4*)Wv + (i-1048576); d4 = (ushort4*)Wqkv  + (i-1048576) + 524288; }
      else if (i < 1572864) { s4 = (const float4*)Wo + (i-1310720); d4 = (ushort4*)Wo_bf + (i-1310720); }
      else                  { s4 = (const float4*)Er + (i-1572864); d4 = (ushort4*)Er_bf + (i-1572864); }
      const float4 v = *s4;
      ushort4 o;
      o.x = f2bf(v.x); o.y = f2bf(v.y); o.z = f2bf(v.z); o.w = f2bf(v.w);
      *d4 = o;
    }
  } else if (bid < 2048) {
    for (int i = (bid - 1024) * 256 + tid; i < 524288; i += 1024 * 256) {
      const int4 a = ((const int4*)rb)[i];
      const int4 b = ((const int4*)rp)[i];
      const int4 c = ((const int4*)ro)[i];
      const int4 d = ((const int4*)rs)[i];
      uint4 r;
      r.x = (unsigned)(a.x | (17+b.x)<<5 | (113+c.x)<<12 | (138+d.x)<<20);
      r.y = (unsigned)(a.y | (17+b.y)<<5 | (113+c.y)<<12 | (138+d.y)<<20);
      r.z = (unsigned)(a.z | (17+b.z)<<5 | (113+c.z)<<12 | (138+d.z)<<20);
      r.w = (unsigned)(a.w | (17+b.w)<<5 | (113+c.w)<<12 | (138+d.w)<<20);
      ((uint4*)Pidx)[i] = r;
    }
  } else {
    for (int t = tid; t < 10240; t += 256) {
      const int s = t >> 6, d = t & 63;
      float v = 0.f;
      if (s < 16)       v = Tb[s * 64 + d];
      else if (s == 16) v = 0.f;
      else if (s < 112) v = Tp[(s - 17) * 64 + d];
      else if (s < 113) v = 0.f;
      else if (s < 137) v = To[(s - 113) * 64 + d];
      else if (s < 138) v = 0.f;
      else if (s < 150) v = Ts[(s - 138) * 64 + d];
      Tpad[t] = f2bf(v * 0.125f);
    }
  }
}

// ---------------------------------------------------------------------------
// m97-style GEMM, block tile 128 x BN (BN in {64,128}), BK=32.
// 4 waves 2x2: wave = 64 rows x BN/2 cols (NT = BN/32 n-tiles of 16).
// MODE 1: f32 row-major out; 2: bf16 QKV head-major scatter.
// ---------------------------------------------------------------------------
__device__ __forceinline__ void ld_lds16(const unsigned short* g, unsigned short* l) {
  __builtin_amdgcn_global_load_lds(
      (const __attribute__((address_space(1))) unsigned int*)g,
      (__attribute__((address_space(3))) unsigned int*)l, 16, 0, 0);
}

template <int MODE, int BN>
__global__ __launch_bounds__(256) void gemm128(const unsigned short* __restrict__ A,
                                               const unsigned short* __restrict__ B,
                                               void* __restrict__ Cv,
                                               int M, int N, int K)
{
  constexpr int NT = BN / 32;  // n-tiles per wave
  __shared__ __align__(16) unsigned short Atile[128 * 32];
  __shared__ __align__(16) unsigned short Btile[BN * 32];
  const int tid = threadIdx.x;
  const int w = tid >> 6, lane = tid & 63;
  const int c15 = lane & 15, q = lane >> 4;
  const int wr = w >> 1, wc = w & 1;
  const int n0 = blockIdx.x * BN, m0 = blockIdx.y * 128;

  const unsigned short* ag = A + (size_t)(m0 + (tid >> 2)) * K + (tid & 3) * 8;
  const unsigned short* bg = B + (size_t)(n0 + (tid >> 2)) * K + (tid & 3) * 8;
  unsigned short* al = &Atile[tid * 8];
  unsigned short* bl = &Btile[tid * 8];
  const size_t half = (size_t)64 * K;

  f32x4 acc[4][NT];
  #pragma unroll
  for (int mt = 0; mt < 4; mt++)
    #pragma unroll
    for (int nt = 0; nt < NT; nt++) { acc[mt][nt][0]=0.f; acc[mt][nt][1]=0.f; acc[mt][nt][2]=0.f; acc[mt][nt][3]=0.f; }

  for (int k0 = 0; k0 < K; k0 += 32) {
    __syncthreads();
    ld_lds16(ag + k0, al);
    ld_lds16(ag + half + k0, al + 2048);
    ld_lds16(bg + k0, bl);
    if constexpr (BN == 128) ld_lds16(bg + half + k0, bl + 2048);
    __syncthreads();

    bf16x8 af[4], bfr[NT];
    #pragma unroll
    for (int mt = 0; mt < 4; mt++)
      af[mt] = *(const bf16x8*)&Atile[(wr * 64 + mt * 16 + c15) * 32 + q * 8];
    #pragma unroll
    for (int nt = 0; nt < NT; nt++)
      bfr[nt] = *(const bf16x8*)&Btile[(wc * (BN / 2) + nt * 16 + c15) * 32 + q * 8];
    #pragma unroll
    for (int mt = 0; mt < 4; mt++)
      #pragma unroll
      for (int nt = 0; nt < NT; nt++)
        acc[mt][nt] = __builtin_amdgcn_mfma_f32_16x16x32_bf16(af[mt], bfr[nt], acc[mt][nt], 0, 0, 0);
  }

  #pragma unroll
  for (int mt = 0; mt < 4; mt++)
    #pragma unroll
    for (int nt = 0; nt < NT; nt++)
      #pragma unroll
      for (int r = 0; r < 4; r++) {
        const int m = m0 + wr * 64 + mt * 16 + q * 4 + r;
        const int n = n0 + wc * (BN / 2) + nt * 16 + c15;
        if constexpr (MODE == 1) {
          ((float*)Cv)[(size_t)m * N + n] = acc[mt][nt][r];
        } else {
          const int which = n >> 10, hh = (n >> 6) & 15, d = n & 63;
          const int bb = m >> 10, i = m & 1023;
          ((unsigned short*)Cv)[(size_t)which * 2097152 +
                                (((size_t)(bb << 4) + hh) << 16) + (i << 6) + d] = f2bf(acc[mt][nt][r]);
        }
      }
}

// ---------------------------------------------------------------------------
// V (b,h,n,64) -> Vt (b,h,64,n); grid 512 (32 bh x 16 i-tiles), block 256.
// [r8-verified]
// ---------------------------------------------------------------------------
__global__ __launch_bounds__(256) void transpose_v(const unsigned short* __restrict__ V,
                                                   unsigned short* __restrict__ Vt)
{
  __shared__ unsigned short T[64][72];
  const int bh = blockIdx.x >> 4;
  const int i0 = (blockIdx.x & 15) << 6;
  const int tid = threadIdx.x;
  const int row = tid >> 2, cs = (tid & 3) * 16;
  const unsigned short* src = V + ((size_t)bh << 16) + ((size_t)(i0 + row) << 6) + cs;
  *(bf16x8*)&T[row][cs]     = *(const bf16x8*)src;
  *(bf16x8*)&T[row][cs + 8] = *(const bf16x8*)(src + 8);
  __syncthreads();
  B8 o0, o1;
  #pragma unroll
  for (int e = 0; e < 8; e++) { o0.u[e] = T[cs + e][row]; o1.u[e] = T[cs + 8 + e][row]; }
  unsigned short* dst = Vt + ((size_t)bh << 16) + ((size_t)row << 10) + i0 + cs;
  *(bf16x8*)dst       = o0.v;
  *(bf16x8*)(dst + 8) = o1.v;
}

// ---------------------------------------------------------------------------
// QE[(bh,i)][s] = Qrow . Tpad[s]  (Tpad pre-scaled 1/8) -> fp16, stride 160.
// ---------------------------------------------------------------------------
__global__ __launch_bounds__(256) void qe_gemm(const unsigned short* __restrict__ Qh,
                                               const unsigned short* __restrict__ Tpad,
                                               unsigned short* __restrict__ QE)
{
  __shared__ __align__(16) unsigned short T[160][72];  // +8 pad
  const int tid = threadIdx.x;
  const int w = tid >> 6, lane = tid & 63;
  const int c15 = lane & 15, q = lane >> 4;
  const int m0 = blockIdx.x * 64 + w * 16;

  for (int t = tid; t < 1280; t += 256) {
    const int r = t >> 3, c = (t & 7) * 8;
    *(bf16x8*)&T[r][c] = *(const bf16x8*)(Tpad + r * 64 + c);
  }
  __syncthreads();

  bf16x8 a0, a1;
  {
    const unsigned short* ap = Qh + ((size_t)(m0 + c15) << 6) + q * 8;
    a0 = *(const bf16x8*)ap;
    a1 = *(const bf16x8*)(ap + 32);
  }
  unsigned short* out = QE + (size_t)m0 * 160;
  #pragma unroll
  for (int st = 0; st < 10; st++) {
    bf16x8 b0 = *(const bf16x8*)&T[st * 16 + c15][q * 8];
    bf16x8 b1 = *(const bf16x8*)&T[st * 16 + c15][32 + q * 8];
    f32x4 acc; acc[0]=0.f; acc[1]=0.f; acc[2]=0.f; acc[3]=0.f;
    acc = __builtin_amdgcn_mfma_f32_16x16x32_bf16(a0, b0, acc, 0, 0, 0);
    acc = __builtin_amdgcn_mfma_f32_16x16x32_bf16(a1, b1, acc, 0, 0, 0);
    #pragma unroll
    for (int r = 0; r < 4; r++) {
      const _Float16 hv = (_Float16)acc[r];
      unsigned short hb;
      __builtin_memcpy(&hb, &hv, 2);
      out[(size_t)(q * 4 + r) * 160 + st * 16 + c15] = hb;
    }
  }
}

// ---------------------------------------------------------------------------
// Flash attention, BARRIER-FREE jt loop.
// grid (h=16, y=16, b=2) = 512; block 256 = 4 waves; wave w owns i-rows
// iw..iw+15. it flipped for bb==1 -> co-resident (long,short) pairs.
// Per iter, per wave: K B-frags from global (per nt the wave covers exactly
// 2 KB contiguous -> coalesced, L2-hot), V^T frags from Vt (r8-verified),
// Er frags from global; per-wave C2 scratch (Srel + P roundtrip); qeh
// read-only after the single post-stage barrier. No block-shared mutable
// LDS in the loop -> zero __syncthreads -> waves pipeline independently.
// LDS 31744 B (qeh 20480 + C2 11264).
// ---------------------------------------------------------------------------
__global__ __launch_bounds__(256) void attn_kernel(
    const unsigned short* __restrict__ QKVh,  // head-major: Q | K | V
    const unsigned short* __restrict__ Vt,    // (b,h,64,n)
    const unsigned short* __restrict__ QE,    // fp16 bits, stride 160
    const unsigned* __restrict__ Pidx,
    const unsigned short* __restrict__ Er,
    unsigned short* __restrict__ Ob)
{
  const int h  = blockIdx.x;
  const int bb = blockIdx.z;
  const int it = bb ? (15 - (int)blockIdx.y) : (int)blockIdx.y;  // co-residency pairing
  const int i0 = it << 6;
  const int tid = threadIdx.x;
  const int w = tid >> 6;
  const int lane = tid & 63;
  const int c15 = lane & 15;
  const int q = lane >> 4;
  const int rowq = q * 4;

  __shared__ __align__(16) unsigned short C2[4][16 * 88];   // per-wave scratch (bf16)
  __shared__ __align__(16) unsigned short qeh[64 * 160];    // QE rows (fp16 bits), RO after stage
  unsigned short* c2w = &C2[w][0];

  const unsigned short* qhb  = QKVh + (((size_t)(bb << 4) + h) << 16);
  const unsigned short* khb  = qhb + 2097152;
  const unsigned short* vthb = Vt + (((size_t)(bb << 4) + h) << 16);

  // ---- stage QE rows (64 x 160 fp16 = 20480 B), vectorized ----
  {
    const size_t qeoff = ((((size_t)(bb << 4) + h) * 1024) + i0) * 160;
    const unsigned short* src = QE + qeoff;
    for (int t = tid; t < 1280; t += 256)
      *(bf16x8*)&qeh[t * 8] = *(const bf16x8*)(src + t * 8);
  }

  // ---- Q fragments, pre-scaled by 1/sqrt(d)=1/8 ----
  bf16x8 qf[2];
  {
    const unsigned short* qp = qhb + ((size_t)(i0 + w * 16 + c15) << 6);
    #pragma unroll
    for (int kk = 0; kk < 2; kk++) {
      B8 t;
      t.v = *(const bf16x8*)(qp + kk * 32 + q * 8);
      #pragma unroll
      for (int e = 0; e < 8; e++) t.u[e] = f2bf(bf2f(t.u[e]) * 0.125f);
      qf[kk] = t.v;
    }
  }

  f32x4 Oa[4];
  float mrow[4], lrow[4];
  #pragma unroll
  for (int dt = 0; dt < 4; dt++) { Oa[dt][0]=0.f; Oa[dt][1]=0.f; Oa[dt][2]=0.f; Oa[dt][3]=0.f; }
  #pragma unroll
  for (int r = 0; r < 4; r++) { mrow[r] = -3e38f; lrow[r] = 0.f; }

  const int iw = i0 + w * 16;
  const size_t idx0 = ((size_t)bb << 20) + ((size_t)(iw + rowq) << 10);

  __syncthreads();  // qeh visible to all waves; ONLY barrier in this kernel

  for (int jt = 0; jt <= it; jt++) {
    const int j0 = jt << 6;

    // ---- QK^T: K B-frags straight from global (2 KB contiguous per nt) ----
    f32x4 S[4];
    #pragma unroll
    for (int nt = 0; nt < 4; nt++) {
      const unsigned short* kp = khb + ((size_t)(j0 + nt * 16 + c15) << 6) + q * 8;
      bf16x8 k0 = *(const bf16x8*)kp;
      bf16x8 k1 = *(const bf16x8*)(kp + 32);
      f32x4 a; a[0]=0.f; a[1]=0.f; a[2]=0.f; a[3]=0.f;
      a = __builtin_amdgcn_mfma_f32_16x16x32_bf16(qf[0], k0, a, 0, 0, 0);
      a = __builtin_amdgcn_mfma_f32_16x16x32_bf16(qf[1], k1, a, 0, 0, 0);
      S[nt] = a;
    }

    // ---- C2 = q . Er-band (Er B-frags from global; 5 of 8 tiles/wave) ----
    {
      const int rbase = 960 - i0 + j0;
      #pragma unroll
      for (int t5 = 0; t5 < 5; t5++) {
        const int pt = 3 - w + t5;
        int row = rbase + pt * 16 + c15;
        row = row > 1023 ? 1023 : row;   // masked-region overrun clamp
        const unsigned short* ep = Er + (row << 6) + q * 8;
        bf16x8 e0 = *(const bf16x8*)ep;
        bf16x8 e1 = *(const bf16x8*)(ep + 32);
        f32x4 a; a[0]=0.f; a[1]=0.f; a[2]=0.f; a[3]=0.f;
        a = __builtin_amdgcn_mfma_f32_16x16x32_bf16(qf[0], e0, a, 0, 0, 0);
        a = __builtin_amdgcn_mfma_f32_16x16x32_bf16(qf[1], e1, a, 0, 0, 0);
        #pragma unroll
        for (int r = 0; r < 4; r++)
          c2w[(rowq + r) * 88 + t5 * 16 + c15] = f2bf(a[r]);
      }
    }

    // ---- scores: + Srel + structure bias (LDS fp16 gathers), causal ----
    #pragma unroll
    for (int nt = 0; nt < 4; nt++) {
      const int j = j0 + nt * 16 + c15;
      unsigned pv[4];
      #pragma unroll
      for (int r = 0; r < 4; r++)
        pv[r] = Pidx[idx0 + ((size_t)r << 10) + j];
      #pragma unroll
      for (int r = 0; r < 4; r++) {
        const int rb = (w * 16 + rowq + r) * 160;
        const unsigned p = pv[r];
        _Float16 q0, q1, q2, q3;
        __builtin_memcpy(&q0, &qeh[rb + (p & 31)], 2);
        __builtin_memcpy(&q1, &qeh[rb + ((p >> 5) & 127)], 2);
        __builtin_memcpy(&q2, &qeh[rb + ((p >> 12) & 255)], 2);
        __builtin_memcpy(&q3, &qeh[rb + (p >> 20)], 2);
        const float bias = (float)(q0 + q1) + (float)(q2 + q3);
        const float srel = bf2f(c2w[(rowq + r) * 88 + (15 - (rowq + r) + nt * 16 + c15)]);
        float sc = S[nt][r] + srel + bias;
        if (jt == it && j > iw + rowq + r) sc = -3e38f;  // causal
        S[nt][r] = sc;
      }
    }

    // ---- online softmax ----
    float alpha[4];
    #pragma unroll
    for (int r = 0; r < 4; r++) {
      float v = fmaxf(fmaxf(S[0][r], S[1][r]), fmaxf(S[2][r], S[3][r]));
      v = fmaxf(v, __shfl_xor(v, 1));
      v = fmaxf(v, __shfl_xor(v, 2));
      v = fmaxf(v, __shfl_xor(v, 4));
      v = fmaxf(v, __shfl_xor(v, 8));
      const float mn = fmaxf(mrow[r], v);
      alpha[r] = __expf(mrow[r] - mn);
      mrow[r] = mn;
    }
    #pragma unroll
    for (int nt = 0; nt < 4; nt++)
      #pragma unroll
      for (int r = 0; r < 4; r++)
        S[nt][r] = __expf(S[nt][r] - mrow[r]);
    #pragma unroll
    for (int r = 0; r < 4; r++) {
      float s = S[0][r] + S[1][r] + S[2][r] + S[3][r];
      s += __shfl_xor(s, 1);
      s += __shfl_xor(s, 2);
      s += __shfl_xor(s, 4);
      s += __shfl_xor(s, 8);
      lrow[r] = lrow[r] * alpha[r] + s;
      #pragma unroll
      for (int dt = 0; dt < 4; dt++) Oa[dt][r] *= alpha[r];
    }

    // ---- P round-trip (per-wave LDS, bf16; read back as ds_read_b128) ----
    #pragma unroll
    for (int nt = 0; nt < 4; nt++)
      #pragma unroll
      for (int r = 0; r < 4; r++)
        c2w[(rowq + r) * 88 + nt * 16 + c15] = f2bf(S[nt][r]);

    bf16x8 pf[2];
    #pragma unroll
    for (int kk = 0; kk < 2; kk++)
      pf[kk] = *(const bf16x8*)&c2w[c15 * 88 + kk * 32 + q * 8];

    // ---- O += P @ V (V^T B-frags from global Vt; r8-verified indexing) ----
    #pragma unroll
    for (int dt = 0; dt < 4; dt++) {
      const unsigned short* vp = vthb + ((size_t)(dt * 16 + c15) << 10) + j0 + q * 8;
      bf16x8 v0 = *(const bf16x8*)vp;
      bf16x8 v1 = *(const bf16x8*)(vp + 32);
      Oa[dt] = __builtin_amdgcn_mfma_f32_16x16x32_bf16(pf[0], v0, Oa[dt], 0, 0, 0);
      Oa[dt] = __builtin_amdgcn_mfma_f32_16x16x32_bf16(pf[1], v1, Oa[dt], 0, 0, 0);
    }
  }

  // ---- epilogue: O / l -> Ob (b, i, h*64+d) bf16 ----
  #pragma unroll
  for (int dt = 0; dt < 4; dt++)
    #pragma unroll
    for (int r = 0; r < 4; r++) {
      const int i_ = iw + rowq + r;
      const float o = Oa[dt][r] / lrow[r];
      Ob[(((size_t)bb << 10) + i_) * 1024 + (h << 6) + dt * 16 + c15] = f2bf(o);
    }
}

// ---------------------------------------------------------------------------
extern "C" void kernel_launch(void* const* d_in, const int* in_sizes, int n_in,
                              void* d_out, int out_size, void* d_ws, size_t ws_size,
                              hipStream_t stream)
{
  const float* x    = (const float*)d_in[0];
  const int*   rbar = (const int*)d_in[1];
  const int*   rpos = (const int*)d_in[2];
  const int*   roct = (const int*)d_in[3];
  const int*   rsem = (const int*)d_in[4];
  const float* Wq   = (const float*)d_in[5];
  const float* Wk   = (const float*)d_in[6];
  const float* Wv   = (const float*)d_in[7];
  const float* Wo   = (const float*)d_in[8];
  const float* Er   = (const float*)d_in[9];
  const float* Tb   = (const float*)d_in[10];
  const float* Tp   = (const float*)d_in[11];
  const float* To   = (const float*)d_in[12];
  const float* Ts   = (const float*)d_in[13];
  float* out = (float*)d_out;

  // workspace layout (~47 MB)
  char* ws = (char*)d_ws;
  const size_t MB = 1u << 20;
  unsigned short* x_bf    = (unsigned short*)(ws);             //  4 MB; dead after QKV gemm
  unsigned short* Vt      = (unsigned short*)(ws);             //  reuses x_bf region (4 MB)
  unsigned short* Wqkv_bf = (unsigned short*)(ws + 4 * MB);    //  6 MB
  unsigned short* Wo_bf   = (unsigned short*)(ws + 10 * MB);   //  2 MB
  unsigned short* Er_bf   = (unsigned short*)(ws + 12 * MB);   //  128 KB
  unsigned short* Tpad    = (unsigned short*)(ws + 12 * MB + 256 * 1024);  // 20 KB
  unsigned short* QKVh    = (unsigned short*)(ws + 13 * MB);   // 12 MB (head-major Q|K|V)
  unsigned short* Ob      = (unsigned short*)(ws + 25 * MB);   //  4 MB
  unsigned short* QE      = (unsigned short*)(ws + 29 * MB);   // 10 MB (fp16 bits, stride 160)
  unsigned*       Pidx    = (unsigned*)(ws + 39 * MB);         //  8 MB

  prep<<<2049, 256, 0, stream>>>(x, Wq, Wk, Wv, Wo, Er, rbar, rpos, roct, rsem,
                                 Tb, Tp, To, Ts,
                                 x_bf, Wqkv_bf, Wo_bf, Er_bf, Pidx, Tpad);

  gemm128<2, 64><<<dim3(48, 16), 256, 0, stream>>>(x_bf, Wqkv_bf, QKVh, 2048, 3072, 1024);
  transpose_v<<<512, 256, 0, stream>>>(QKVh + 2 * 2097152, Vt);  // x_bf dead now
  qe_gemm<<<512, 256, 0, stream>>>(QKVh, Tpad, QE);
  attn_kernel<<<dim3(16, 16, 2), 256, 0, stream>>>(QKVh, Vt, QE, Pidx, Er_bf, Ob);
  gemm128<1, 64><<<dim3(16, 16), 256, 0, stream>>>(Ob, Wo_bf, out, 2048, 1024, 1024);
}

// Round 11
// 240.881 us; speedup vs baseline: 1.2092x; 1.2092x over previous
//
#include <hip/hip_runtime.h>

// ---------------------------------------------------------------------------
// RelativeStructureAttention (Music-Transformer style) on MI355X / gfx950.
//   b=2, n=1024, dim=1024, HEADS=16, d_h=64. Inputs fp32 (+int32 idx), out fp32.
// Pipeline (round 11 = r9 attn + inline QE + BN=64 gemms, 4 launches):
//   0) prep        fused cast / pack_idx / build_tpad (Tpad UNSCALED: attn
//                  computes qe with qf which already carries the 1/8)
//   1) gemm<2,64>  x@Wqkv^T -> QKVh (bf16, head-major), grid 768 (3/CU)
//   2) attn        r9 body (async K dbuf via global_load_lds) + per-wave QE
//                  rows computed in-prologue via MFMA (qe_gemm launch + 20 MB
//                  of QE HBM traffic deleted)
//   3) gemm<1,64>  O@Wo^T -> d_out (fp32), grid 256 (1/CU, was 0.5)
// ---------------------------------------------------------------------------

using bf16x8 = __attribute__((ext_vector_type(8))) short;
using f32x4  = __attribute__((ext_vector_type(4))) float;

__device__ __forceinline__ float bf2f(unsigned short u) {
  unsigned x = ((unsigned)u) << 16;
  float f;
  __builtin_memcpy(&f, &x, 4);
  return f;
}
__device__ __forceinline__ unsigned short f2bf(float f) {
  unsigned x;
  __builtin_memcpy(&x, &f, 4);
  unsigned r = (x + 0x7FFFu + ((x >> 16) & 1u)) >> 16;  // round-nearest-even
  return (unsigned short)r;
}

union B8 { bf16x8 v; unsigned short u[8]; };

// ---------------------------------------------------------------------------
// prep: blocks 0..1023 cast six fp32 tensors -> bf16; 1024..2047 pack idx;
//       block 2048 builds the padded 160x64 structure table (UNSCALED).
// ---------------------------------------------------------------------------
__global__ __launch_bounds__(256) void prep(
    const float* __restrict__ x,  const float* __restrict__ Wq,
    const float* __restrict__ Wk, const float* __restrict__ Wv,
    const float* __restrict__ Wo, const float* __restrict__ Er,
    const int* __restrict__ rb, const int* __restrict__ rp,
    const int* __restrict__ ro, const int* __restrict__ rs,
    const float* __restrict__ Tb, const float* __restrict__ Tp,
    const float* __restrict__ To, const float* __restrict__ Ts,
    unsigned short* __restrict__ x_bf, unsigned short* __restrict__ Wqkv,
    unsigned short* __restrict__ Wo_bf, unsigned short* __restrict__ Er_bf,
    unsigned* __restrict__ Pidx, unsigned short* __restrict__ Tpad)
{
  const int bid = blockIdx.x;
  const int tid = threadIdx.x;
  if (bid < 1024) {
    const int total = 1589248;  // 6,356,992 floats / 4
    for (int i = bid * 256 + tid; i < total; i += 1024 * 256) {
      const float4* s4;
      ushort4* d4;
      if (i < 524288)       { s4 = (const float4*)x  + i;           d4 = (ushort4*)x_bf  + i; }
      else if (i < 786432)  { s4 = (const float4*)Wq + (i-524288);  d4 = (ushort4*)Wqkv  + (i-524288); }
      else if (i < 1048576) { s4 = (const float4*)Wk + (i-786432);  d4 = (ushort4*)Wqkv  + (i-786432) + 262144; }
      else if (i < 1310720) { s4 = (const float4*)Wv + (i-1048576); d4 = (ushort4*)Wqkv  + (i-1048576) + 524288; }
      else if (i < 1572864) { s4 = (const float4*)Wo + (i-1310720); d4 = (ushort4*)Wo_bf + (i-1310720); }
      else                  { s4 = (const float4*)Er + (i-1572864); d4 = (ushort4*)Er_bf + (i-1572864); }
      const float4 v = *s4;
      ushort4 o;
      o.x = f2bf(v.x); o.y = f2bf(v.y); o.z = f2bf(v.z); o.w = f2bf(v.w);
      *d4 = o;
    }
  } else if (bid < 2048) {
    for (int i = (bid - 1024) * 256 + tid; i < 524288; i += 1024 * 256) {
      const int4 a = ((const int4*)rb)[i];
      const int4 b = ((const int4*)rp)[i];
      const int4 c = ((const int4*)ro)[i];
      const int4 d = ((const int4*)rs)[i];
      uint4 r;
      r.x = (unsigned)(a.x | (17+b.x)<<5 | (113+c.x)<<12 | (138+d.x)<<20);
      r.y = (unsigned)(a.y | (17+b.y)<<5 | (113+c.y)<<12 | (138+d.y)<<20);
      r.z = (unsigned)(a.z | (17+b.z)<<5 | (113+c.z)<<12 | (138+d.z)<<20);
      r.w = (unsigned)(a.w | (17+b.w)<<5 | (113+c.w)<<12 | (138+d.w)<<20);
      ((uint4*)Pidx)[i] = r;
    }
  } else {
    // padded structure table: s [0..15]=bar,16=0,[17..111]=pos,112=0,
    // [113..136]=oct,137=0,[138..149]=sem,150..159=0. UNSCALED (qf has 1/8).
    for (int t = tid; t < 10240; t += 256) {
      const int s = t >> 6, d = t & 63;
      float v = 0.f;
      if (s < 16)       v = Tb[s * 64 + d];
      else if (s == 16) v = 0.f;
      else if (s < 112) v = Tp[(s - 17) * 64 + d];
      else if (s < 113) v = 0.f;
      else if (s < 137) v = To[(s - 113) * 64 + d];
      else if (s < 138) v = 0.f;
      else if (s < 150) v = Ts[(s - 138) * 64 + d];
      Tpad[t] = f2bf(v);
    }
  }
}

// ---------------------------------------------------------------------------
// m97-style GEMM, block tile 128 x BN (BN in {64,128}), BK=32.
// MODE 1: f32 row-major out; 2: bf16 QKV head-major scatter.
// ---------------------------------------------------------------------------
__device__ __forceinline__ void ld_lds16(const unsigned short* g, unsigned short* l) {
  __builtin_amdgcn_global_load_lds(
      (const __attribute__((address_space(1))) unsigned int*)g,
      (__attribute__((address_space(3))) unsigned int*)l, 16, 0, 0);
}

template <int MODE, int BN>
__global__ __launch_bounds__(256) void gemm128(const unsigned short* __restrict__ A,
                                               const unsigned short* __restrict__ B,
                                               void* __restrict__ Cv,
                                               int M, int N, int K)
{
  constexpr int NT = BN / 32;  // n-tiles per wave
  __shared__ __align__(16) unsigned short Atile[128 * 32];
  __shared__ __align__(16) unsigned short Btile[BN * 32];
  const int tid = threadIdx.x;
  const int w = tid >> 6, lane = tid & 63;
  const int c15 = lane & 15, q = lane >> 4;
  const int wr = w >> 1, wc = w & 1;
  const int n0 = blockIdx.x * BN, m0 = blockIdx.y * 128;

  const unsigned short* ag = A + (size_t)(m0 + (tid >> 2)) * K + (tid & 3) * 8;
  const unsigned short* bg = B + (size_t)(n0 + (tid >> 2)) * K + (tid & 3) * 8;
  unsigned short* al = &Atile[tid * 8];
  unsigned short* bl = &Btile[tid * 8];
  const size_t half = (size_t)64 * K;

  f32x4 acc[4][NT];
  #pragma unroll
  for (int mt = 0; mt < 4; mt++)
    #pragma unroll
    for (int nt = 0; nt < NT; nt++) { acc[mt][nt][0]=0.f; acc[mt][nt][1]=0.f; acc[mt][nt][2]=0.f; acc[mt][nt][3]=0.f; }

  for (int k0 = 0; k0 < K; k0 += 32) {
    __syncthreads();
    ld_lds16(ag + k0, al);
    ld_lds16(ag + half + k0, al + 2048);
    ld_lds16(bg + k0, bl);
    if constexpr (BN == 128) ld_lds16(bg + half + k0, bl + 2048);
    __syncthreads();

    bf16x8 af[4], bfr[NT];
    #pragma unroll
    for (int mt = 0; mt < 4; mt++)
      af[mt] = *(const bf16x8*)&Atile[(wr * 64 + mt * 16 + c15) * 32 + q * 8];
    #pragma unroll
    for (int nt = 0; nt < NT; nt++)
      bfr[nt] = *(const bf16x8*)&Btile[(wc * (BN / 2) + nt * 16 + c15) * 32 + q * 8];
    #pragma unroll
    for (int mt = 0; mt < 4; mt++)
      #pragma unroll
      for (int nt = 0; nt < NT; nt++)
        acc[mt][nt] = __builtin_amdgcn_mfma_f32_16x16x32_bf16(af[mt], bfr[nt], acc[mt][nt], 0, 0, 0);
  }

  #pragma unroll
  for (int mt = 0; mt < 4; mt++)
    #pragma unroll
    for (int nt = 0; nt < NT; nt++)
      #pragma unroll
      for (int r = 0; r < 4; r++) {
        const int m = m0 + wr * 64 + mt * 16 + q * 4 + r;
        const int n = n0 + wc * (BN / 2) + nt * 16 + c15;
        if constexpr (MODE == 1) {
          ((float*)Cv)[(size_t)m * N + n] = acc[mt][nt][r];
        } else {
          const int which = n >> 10, hh = (n >> 6) & 15, d = n & 63;
          const int bb = m >> 10, i = m & 1023;
          ((unsigned short*)Cv)[(size_t)which * 2097152 +
                                (((size_t)(bb << 4) + hh) << 16) + (i << 6) + d] = f2bf(acc[mt][nt][r]);
        }
      }
}

// ---------------------------------------------------------------------------
// Flash attention (r9 body: async K double-buffer + inline per-wave QE).
// grid (h=16, y=16, b=2) = 512 blocks; block 256 = 4 waves; wave w owns
// i-rows iw..iw+15. it flipped for bb==1 -> co-resident (long,short) pairs.
// LDS 57344 B: Klds dbuf 2x8192 (unpadded lane-order, global_load_lds),
// Vtlds 9216 (+8 pad), C2 11264, qeh 20480. K tile jt+1 DMA'd right after
// the top barrier -> L2 latency overlaps QK/Srel/bias/softmax of tile jt.
// qeh computed in-prologue: wave w's 16 QE rows = qf . Tpad (20 MFMA);
// gathers only ever touch the owning wave's rows -> no barrier needed.
// Srel via Er B-frags from global: rbase = 960-i0+j0, wave w tiles
// pt=3-w..7-w, readback col 15-m+jj. Bias: packed idx + 4 LDS fp16 gathers.
// ---------------------------------------------------------------------------
__global__ __launch_bounds__(256) void attn_kernel(
    const unsigned short* __restrict__ QKVh,  // head-major: Q | K | V
    const unsigned short* __restrict__ Tpad,  // 160 x 64 bf16, unscaled
    const unsigned* __restrict__ Pidx,
    const unsigned short* __restrict__ Er,
    unsigned short* __restrict__ Ob)
{
  const int h  = blockIdx.x;
  const int bb = blockIdx.z;
  const int it = bb ? (15 - (int)blockIdx.y) : (int)blockIdx.y;  // co-residency pairing
  const int i0 = it << 6;
  const int tid = threadIdx.x;
  const int w = tid >> 6;
  const int lane = tid & 63;
  const int c15 = lane & 15;
  const int q = lane >> 4;
  const int rowq = q * 4;

  __shared__ __align__(16) unsigned short Klds[2][64 * 64];  // dbuf, lane-order
  __shared__ __align__(16) unsigned short Vtlds[64][72];     // V^T: [d][j], +8 pad
  __shared__ __align__(16) unsigned short C2[4][16 * 88];    // per-wave scratch (bf16)
  __shared__ __align__(16) unsigned short qeh[64 * 160];     // QE rows (fp16), per-wave
  unsigned short* c2w = &C2[w][0];

  const unsigned short* qhb = QKVh + (((size_t)(bb << 4) + h) << 16);
  const unsigned short* khb = qhb + 2097152;
  const unsigned short* vhb = qhb + 2 * 2097152;

  // ---- prologue: async-stage K tile 0 into buf 0 ----
  ld_lds16(khb + tid * 8,        &Klds[0][tid * 8]);
  ld_lds16(khb + 2048 + tid * 8, &Klds[0][2048 + tid * 8]);

  // ---- Q fragments, pre-scaled by 1/sqrt(d)=1/8 ----
  bf16x8 qf[2];
  {
    const unsigned short* qp = qhb + ((size_t)(i0 + w * 16 + c15) << 6);
    #pragma unroll
    for (int kk = 0; kk < 2; kk++) {
      B8 t;
      t.v = *(const bf16x8*)(qp + kk * 32 + q * 8);
      #pragma unroll
      for (int e = 0; e < 8; e++) t.u[e] = f2bf(bf2f(t.u[e]) * 0.125f);
      qf[kk] = t.v;
    }
  }

  // ---- compute this wave's 16 QE rows via MFMA: qe = (q/8) . Tpad ----
  #pragma unroll
  for (int st = 0; st < 10; st++) {
    const unsigned short* tp = Tpad + (size_t)(st * 16 + c15) * 64 + q * 8;
    bf16x8 t0 = *(const bf16x8*)tp;
    bf16x8 t1 = *(const bf16x8*)(tp + 32);
    f32x4 a; a[0]=0.f; a[1]=0.f; a[2]=0.f; a[3]=0.f;
    a = __builtin_amdgcn_mfma_f32_16x16x32_bf16(qf[0], t0, a, 0, 0, 0);
    a = __builtin_amdgcn_mfma_f32_16x16x32_bf16(qf[1], t1, a, 0, 0, 0);
    #pragma unroll
    for (int r = 0; r < 4; r++) {
      const _Float16 hv = (_Float16)a[r];
      unsigned short hb;
      __builtin_memcpy(&hb, &hv, 2);
      qeh[(w * 16 + rowq + r) * 160 + st * 16 + c15] = hb;
    }
  }

  f32x4 Oa[4];
  float mrow[4], lrow[4];
  #pragma unroll
  for (int dt = 0; dt < 4; dt++) { Oa[dt][0]=0.f; Oa[dt][1]=0.f; Oa[dt][2]=0.f; Oa[dt][3]=0.f; }
  #pragma unroll
  for (int r = 0; r < 4; r++) { mrow[r] = -3e38f; lrow[r] = 0.f; }

  const int iw = i0 + w * 16;
  const size_t idx0 = ((size_t)bb << 20) + ((size_t)(iw + rowq) << 10);

  for (int jt = 0; jt <= it; jt++) {
    const int j0 = jt << 6;
    const int cur = jt & 1;

    __syncthreads();  // K[cur] staged & visible; prev-iter LDS consumers done

    // ---- async prefetch K tile jt+1 into the other buffer ----
    if (jt < it) {
      const unsigned short* kn = khb + ((jt + 1) << 12);  // (jt+1)*4096 shorts
      ld_lds16(kn + tid * 8,        &Klds[cur ^ 1][tid * 8]);
      ld_lds16(kn + 2048 + tid * 8, &Klds[cur ^ 1][2048 + tid * 8]);
    }

    // ---- Pidx batch (independent; overlaps the compute below) ----
    unsigned pv[4][4];
    #pragma unroll
    for (int nt = 0; nt < 4; nt++)
      #pragma unroll
      for (int r = 0; r < 4; r++)
        pv[nt][r] = Pidx[idx0 + ((size_t)r << 10) + j0 + nt * 16 + c15];

    // ---- stage V^T (scalar scatter into padded Vtlds) ----
    {
      const int vrow = tid >> 2, vcs = (tid & 3) * 16;
      const unsigned short* vt = vhb + (j0 << 6) + (vrow << 6) + vcs;
      B8 v0, v1;
      v0.v = *(const bf16x8*)vt;
      v1.v = *(const bf16x8*)(vt + 8);
      #pragma unroll
      for (int e = 0; e < 8; e++) {
        Vtlds[vcs + e][vrow]     = v0.u[e];
        Vtlds[vcs + 8 + e][vrow] = v1.u[e];
      }
    }

    // ---- QK^T from Klds[cur] (row stride 64 shorts) ----
    f32x4 S[4];
    #pragma unroll
    for (int nt = 0; nt < 4; nt++) {
      f32x4 a; a[0]=0.f; a[1]=0.f; a[2]=0.f; a[3]=0.f;
      bf16x8 k0 = *(const bf16x8*)&Klds[cur][(nt * 16 + c15) * 64 + q * 8];
      bf16x8 k1 = *(const bf16x8*)&Klds[cur][(nt * 16 + c15) * 64 + 32 + q * 8];
      a = __builtin_amdgcn_mfma_f32_16x16x32_bf16(qf[0], k0, a, 0, 0, 0);
      a = __builtin_amdgcn_mfma_f32_16x16x32_bf16(qf[1], k1, a, 0, 0, 0);
      S[nt] = a;
    }

    // ---- C2 = q . Er-band (Er B-frags from global; 5 of 8 tiles/wave) ----
    {
      const int rbase = 960 - i0 + j0;
      #pragma unroll
      for (int t5 = 0; t5 < 5; t5++) {
        const int pt = 3 - w + t5;
        int row = rbase + pt * 16 + c15;
        row = row > 1023 ? 1023 : row;   // masked-region overrun clamp
        const unsigned short* ep = Er + (row << 6) + q * 8;
        bf16x8 e0 = *(const bf16x8*)ep;
        bf16x8 e1 = *(const bf16x8*)(ep + 32);
        f32x4 a; a[0]=0.f; a[1]=0.f; a[2]=0.f; a[3]=0.f;
        a = __builtin_amdgcn_mfma_f32_16x16x32_bf16(qf[0], e0, a, 0, 0, 0);
        a = __builtin_amdgcn_mfma_f32_16x16x32_bf16(qf[1], e1, a, 0, 0, 0);
        #pragma unroll
        for (int r = 0; r < 4; r++)
          c2w[(rowq + r) * 88 + t5 * 16 + c15] = f2bf(a[r]);
      }
    }

    // ---- scores: + Srel + structure bias (LDS fp16 gathers), causal ----
    #pragma unroll
    for (int nt = 0; nt < 4; nt++) {
      const int j = j0 + nt * 16 + c15;
      #pragma unroll
      for (int r = 0; r < 4; r++) {
        const int rb = (w * 16 + rowq + r) * 160;
        const unsigned p = pv[nt][r];
        _Float16 q0, q1, q2, q3;
        __builtin_memcpy(&q0, &qeh[rb + (p & 31)], 2);
        __builtin_memcpy(&q1, &qeh[rb + ((p >> 5) & 127)], 2);
        __builtin_memcpy(&q2, &qeh[rb + ((p >> 12) & 255)], 2);
        __builtin_memcpy(&q3, &qeh[rb + (p >> 20)], 2);
        const float bias = (float)(q0 + q1) + (float)(q2 + q3);
        const float srel = bf2f(c2w[(rowq + r) * 88 + (15 - (rowq + r) + nt * 16 + c15)]);
        float sc = S[nt][r] + srel + bias;
        if (jt == it && j > iw + rowq + r) sc = -3e38f;  // causal
        S[nt][r] = sc;
      }
    }

    // ---- online softmax ----
    float alpha[4];
    #pragma unroll
    for (int r = 0; r < 4; r++) {
      float v = fmaxf(fmaxf(S[0][r], S[1][r]), fmaxf(S[2][r], S[3][r]));
      v = fmaxf(v, __shfl_xor(v, 1));
      v = fmaxf(v, __shfl_xor(v, 2));
      v = fmaxf(v, __shfl_xor(v, 4));
      v = fmaxf(v, __shfl_xor(v, 8));
      const float mn = fmaxf(mrow[r], v);
      alpha[r] = __expf(mrow[r] - mn);
      mrow[r] = mn;
    }
    #pragma unroll
    for (int nt = 0; nt < 4; nt++)
      #pragma unroll
      for (int r = 0; r < 4; r++)
        S[nt][r] = __expf(S[nt][r] - mrow[r]);
    #pragma unroll
    for (int r = 0; r < 4; r++) {
      float s = S[0][r] + S[1][r] + S[2][r] + S[3][r];
      s += __shfl_xor(s, 1);
      s += __shfl_xor(s, 2);
      s += __shfl_xor(s, 4);
      s += __shfl_xor(s, 8);
      lrow[r] = lrow[r] * alpha[r] + s;
      #pragma unroll
      for (int dt = 0; dt < 4; dt++) Oa[dt][r] *= alpha[r];
    }

    __syncthreads();  // all waves' V^T stores visible before PV reads

    // ---- P round-trip (per-wave LDS, bf16; read back as ds_read_b128) ----
    #pragma unroll
    for (int nt = 0; nt < 4; nt++)
      #pragma unroll
      for (int r = 0; r < 4; r++)
        c2w[(rowq + r) * 88 + nt * 16 + c15] = f2bf(S[nt][r]);

    bf16x8 pf[2];
    #pragma unroll
    for (int kk = 0; kk < 2; kk++)
      pf[kk] = *(const bf16x8*)&c2w[c15 * 88 + kk * 32 + q * 8];

    // ---- O += P @ V ----
    #pragma unroll
    for (int dt = 0; dt < 4; dt++) {
      bf16x8 v0 = *(const bf16x8*)&Vtlds[dt * 16 + c15][q * 8];
      bf16x8 v1 = *(const bf16x8*)&Vtlds[dt * 16 + c15][32 + q * 8];
      Oa[dt] = __builtin_amdgcn_mfma_f32_16x16x32_bf16(pf[0], v0, Oa[dt], 0, 0, 0);
      Oa[dt] = __builtin_amdgcn_mfma_f32_16x16x32_bf16(pf[1], v1, Oa[dt], 0, 0, 0);
    }
  }

  // ---- epilogue: O / l -> Ob (b, i, h*64+d) bf16 ----
  #pragma unroll
  for (int dt = 0; dt < 4; dt++)
    #pragma unroll
    for (int r = 0; r < 4; r++) {
      const int i_ = iw + rowq + r;
      const float o = Oa[dt][r] / lrow[r];
      Ob[(((size_t)bb << 10) + i_) * 1024 + (h << 6) + dt * 16 + c15] = f2bf(o);
    }
}

// ---------------------------------------------------------------------------
extern "C" void kernel_launch(void* const* d_in, const int* in_sizes, int n_in,
                              void* d_out, int out_size, void* d_ws, size_t ws_size,
                              hipStream_t stream)
{
  const float* x    = (const float*)d_in[0];
  const int*   rbar = (const int*)d_in[1];
  const int*   rpos = (const int*)d_in[2];
  const int*   roct = (const int*)d_in[3];
  const int*   rsem = (const int*)d_in[4];
  const float* Wq   = (const float*)d_in[5];
  const float* Wk   = (const float*)d_in[6];
  const float* Wv   = (const float*)d_in[7];
  const float* Wo   = (const float*)d_in[8];
  const float* Er   = (const float*)d_in[9];
  const float* Tb   = (const float*)d_in[10];
  const float* Tp   = (const float*)d_in[11];
  const float* To   = (const float*)d_in[12];
  const float* Ts   = (const float*)d_in[13];
  float* out = (float*)d_out;

  // workspace layout (~47 MB)
  char* ws = (char*)d_ws;
  const size_t MB = 1u << 20;
  unsigned short* x_bf    = (unsigned short*)(ws);             //  4 MB
  unsigned short* Wqkv_bf = (unsigned short*)(ws + 4 * MB);    //  6 MB
  unsigned short* Wo_bf   = (unsigned short*)(ws + 10 * MB);   //  2 MB
  unsigned short* Er_bf   = (unsigned short*)(ws + 12 * MB);   //  128 KB
  unsigned short* Tpad    = (unsigned short*)(ws + 12 * MB + 256 * 1024);  // 20 KB
  unsigned short* QKVh    = (unsigned short*)(ws + 13 * MB);   // 12 MB (head-major Q|K|V)
  unsigned short* Ob      = (unsigned short*)(ws + 25 * MB);   //  4 MB
  unsigned*       Pidx    = (unsigned*)(ws + 39 * MB);         //  8 MB

  prep<<<2049, 256, 0, stream>>>(x, Wq, Wk, Wv, Wo, Er, rbar, rpos, roct, rsem,
                                 Tb, Tp, To, Ts,
                                 x_bf, Wqkv_bf, Wo_bf, Er_bf, Pidx, Tpad);

  gemm128<2, 64><<<dim3(48, 16), 256, 0, stream>>>(x_bf, Wqkv_bf, QKVh, 2048, 3072, 1024);
  attn_kernel<<<dim3(16, 16, 2), 256, 0, stream>>>(QKVh, Tpad, Pidx, Er_bf, Ob);
  gemm128<1, 64><<<dim3(16, 16), 256, 0, stream>>>(Ob, Wo_bf, out, 2048, 1024, 1024);
}